// Round 9
// baseline (169.583 us; speedup 1.0000x reference)
//
#include <hip/hip_runtime.h>

#define HD 32
#define NHEADS 12
#define HH 56
#define WW 56
#define NN (HH * WW)
#define BB 8
#define CC (HD * NHEADS)
#define SCALE 0.17677669529663689f
#define NGR 8      // channel groups (threadIdx.y), 4 channels each
#define GCH 4

// Round-9: r8 structure (center-tap float2 loads, DPP side-taps, branchless
// masks) with two changes:
//  1. 4 channels/thread (8-way split) + v-loads issued AFTER the barrier into
//     k's freed registers -> target <=64 VGPR. VGPR plateaus at {64,128,256}
//     (r0/r2/r4/r7 evidence: meas occupancy ~= 0.4x cap, cap 8/4/2 waves);
//     r7's 124 sat mid-plateau, so only crossing 64 raises concurrency.
//  2. XCD swizzle: each XCD (flat%8) gets 336 consecutive work items = 12
//     whole bh-slabs of contiguous stripes -> 3x tap-row re-reads hit the
//     home XCD's L2 instead of HBM (FETCH was 144MB vs 115 ideal).
__device__ __forceinline__ float dpp_up1(float x) {   // lane i <- i-1; lane0 <- 0
    return __int_as_float(
        __builtin_amdgcn_update_dpp(0, __float_as_int(x), 0x138, 0xF, 0xF, true));
}
__device__ __forceinline__ float dpp_dn1(float x) {   // lane i <- i+1; lane63 <- 0
    return __int_as_float(
        __builtin_amdgcn_update_dpp(0, __float_as_int(x), 0x130, 0xF, 0xF, true));
}

__global__ __launch_bounds__(512) void dilate_attn_kernel(
    const float* __restrict__ q,
    const float* __restrict__ k,
    const float* __restrict__ v,
    float* __restrict__ out)
{
    const int tx = threadIdx.x;            // 0..63 (pair within 2-row stripe)
    const int qc = threadIdx.y;            // 0..7 channel group (4 ch)
    const int flat = blockIdx.x;           // 0..2687
    const int work = (flat & 7) * 336 + (flat >> 3);   // bijective: 8*336=2688
    const int stripe = work % 28;
    const int bh     = work / 28;
    const int b = bh / NHEADS;
    const int head = bh - b * NHEADS;

    const int n0r = stripe * 112 + 2 * tx;
    const int n0 = (n0r <= NN - 2) ? n0r : NN - 2;   // clamp idle lanes
    const bool active = (tx < 56);

    const int y  = n0 / WW;
    const int x0 = n0 - y * WW;            // even; stripe base is row-aligned
    const float mlo = (x0 == 0)      ? 0.f : 1.f;
    const float mhi = (x0 == WW - 2) ? 0.f : 1.f;

    const int base0 = (b * CC + head * HD + qc * GCH) * NN;

    __shared__ float2 part[NGR][64][9];    // 36864 B logit exchange

    // ---- prefetch q (4 ch) + k (3 rows x 4 ch): 16 float2 loads ----
    float2 qv[GCH];
#pragma unroll
    for (int d = 0; d < GCH; ++d)
        qv[d] = *reinterpret_cast<const float2*>(q + base0 + d * NN + n0);

    float rm[3]; int rb[3];
#pragma unroll
    for (int r = 0; r < 3; ++r) {
        const int ny = y + (r - 1) * 2;
        rm[r] = ((unsigned)ny < HH) ? 1.f : 0.f;
        const int nyc = ny < 0 ? 0 : (ny > HH - 1 ? HH - 1 : ny);
        rb[r] = base0 + nyc * WW + x0;
    }

    float2 km[3][GCH];
#pragma unroll
    for (int r = 0; r < 3; ++r)
#pragma unroll
        for (int d = 0; d < GCH; ++d)
            km[r][d] = *reinterpret_cast<const float2*>(k + rb[r] + d * NN);

    // ---- QK: center tap local, side taps via DPP wave shifts ----
    float lg[9][2];
#pragma unroll
    for (int r = 0; r < 3; ++r) {
        float s0x = 0.f, s0y = 0.f, s1x = 0.f, s1y = 0.f, s2x = 0.f, s2y = 0.f;
#pragma unroll
        for (int d = 0; d < GCH; ++d) {
            const float2 w1 = km[r][d];
            const float w0x = dpp_up1(w1.x);
            const float w0y = dpp_up1(w1.y);
            const float w2x = dpp_dn1(w1.x);
            const float w2y = dpp_dn1(w1.y);
            s0x = fmaf(qv[d].x, w0x, s0x);  s0y = fmaf(qv[d].y, w0y, s0y);
            s1x = fmaf(qv[d].x, w1.x, s1x); s1y = fmaf(qv[d].y, w1.y, s1y);
            s2x = fmaf(qv[d].x, w2x, s2x);  s2y = fmaf(qv[d].y, w2y, s2y);
        }
        const float m0 = rm[r] * mlo, m2 = rm[r] * mhi;
        lg[r * 3 + 0][0] = s0x * m0;    lg[r * 3 + 0][1] = s0y * m0;
        lg[r * 3 + 1][0] = s1x * rm[r]; lg[r * 3 + 1][1] = s1y * rm[r];
        lg[r * 3 + 2][0] = s2x * m2;    lg[r * 3 + 2][1] = s2y * m2;
    }

    // ---- write partials, barrier ----
#pragma unroll
    for (int t = 0; t < 9; ++t) part[qc][tx][t] = make_float2(lg[t][0], lg[t][1]);
    __syncthreads();

    // ---- issue v loads NOW (into k's freed regs); latency hides under the
    //      8-way combine + softmax below. sched_barrier pins them here. ----
    float2 vm[3][GCH];
#pragma unroll
    for (int r = 0; r < 3; ++r)
#pragma unroll
        for (int d = 0; d < GCH; ++d)
            vm[r][d] = *reinterpret_cast<const float2*>(v + rb[r] + d * NN);
    __builtin_amdgcn_sched_barrier(0);

    // ---- combine the 8 groups via LDS ----
#pragma unroll
    for (int o = 1; o < NGR; ++o) {
        const int oq = (qc + o) & (NGR - 1);
#pragma unroll
        for (int t = 0; t < 9; ++t) {
            const float2 p = part[oq][tx][t];
            lg[t][0] += p.x; lg[t][1] += p.y;
        }
    }

    // ---- softmax over 9 taps (dup per group; cheap) ----
#pragma unroll
    for (int j = 0; j < 2; ++j) {
        float m = lg[0][j] * SCALE;
#pragma unroll
        for (int t = 0; t < 9; ++t) { lg[t][j] *= SCALE; m = fmaxf(m, lg[t][j]); }
        float s = 0.f;
#pragma unroll
        for (int t = 0; t < 9; ++t) { const float e = __expf(lg[t][j] - m); lg[t][j] = e; s += e; }
        const float inv = 1.f / s;
#pragma unroll
        for (int t = 0; t < 9; ++t) lg[t][j] *= inv;
    }
    // re-mask: invalid taps have nonzero softmax weight but v==0 in the ref
#pragma unroll
    for (int r = 0; r < 3; ++r) {
        const float m0 = rm[r] * mlo, m2 = rm[r] * mhi;
        lg[r * 3 + 0][0] *= m0;    lg[r * 3 + 0][1] *= m0;
        lg[r * 3 + 1][0] *= rm[r]; lg[r * 3 + 1][1] *= rm[r];
        lg[r * 3 + 2][0] *= m2;    lg[r * 3 + 2][1] *= m2;
    }

    // ---- PV: center tap local, side taps via DPP wave shifts ----
    float acc[GCH][2];
#pragma unroll
    for (int d = 0; d < GCH; ++d) { acc[d][0] = 0.f; acc[d][1] = 0.f; }
#pragma unroll
    for (int r = 0; r < 3; ++r) {
        const float g0x = lg[r * 3 + 0][0], g0y = lg[r * 3 + 0][1];
        const float g1x = lg[r * 3 + 1][0], g1y = lg[r * 3 + 1][1];
        const float g2x = lg[r * 3 + 2][0], g2y = lg[r * 3 + 2][1];
#pragma unroll
        for (int d = 0; d < GCH; ++d) {
            const float2 u1 = vm[r][d];
            const float u0x = dpp_up1(u1.x);
            const float u0y = dpp_up1(u1.y);
            const float u2x = dpp_dn1(u1.x);
            const float u2y = dpp_dn1(u1.y);
            acc[d][0] = fmaf(g0x, u0x, acc[d][0]);  acc[d][1] = fmaf(g0y, u0y, acc[d][1]);
            acc[d][0] = fmaf(g1x, u1.x, acc[d][0]); acc[d][1] = fmaf(g1y, u1.y, acc[d][1]);
            acc[d][0] = fmaf(g2x, u2x, acc[d][0]);  acc[d][1] = fmaf(g2y, u2y, acc[d][1]);
        }
    }

    // ---- store: out[b, y, x0+j, head*32 + qc*4 + 0..3] ----
    if (active) {
#pragma unroll
        for (int j = 0; j < 2; ++j) {
            float* ob = out + ((b * HH + y) * WW + (x0 + j)) * CC + head * HD + qc * GCH;
            *reinterpret_cast<float4*>(ob) =
                make_float4(acc[0][j], acc[1][j], acc[2][j], acc[3][j]);
        }
    }
}

extern "C" void kernel_launch(void* const* d_in, const int* in_sizes, int n_in,
                              void* d_out, int out_size, void* d_ws, size_t ws_size,
                              hipStream_t stream) {
    const float* q = (const float*)d_in[0];
    const float* k = (const float*)d_in[1];
    const float* v = (const float*)d_in[2];
    float* out = (float*)d_out;

    dim3 block(64, NGR);                  // 512 threads
    dim3 grid(28 * BB * NHEADS);          // 2688 flat; swizzled in-kernel
    dilate_attn_kernel<<<grid, block, 0, stream>>>(q, k, v, out);
}

// Round 10
// 162.264 us; speedup vs baseline: 1.0451x; 1.0451x over previous
//
#include <hip/hip_runtime.h>

#define HD 32
#define NHEADS 12
#define HH 56
#define WW 56
#define NN (HH * WW)
#define BB 8
#define CC (HD * NHEADS)
#define SCALE 0.17677669529663689f

// Round-10 = r8 (best base, 64.5us: center-tap float2 loads, DPP side taps,
// 4-way combine, branchless masks) + two individually-proven r9 wins:
//  1. XCD swizzle (r9: FETCH 144->56MB): flat%8 -> XCD gets 336 consecutive
//     work items = 12 whole bh-slabs -> tap-row re-reads are home-L2 hits
//     (~200-300cy) instead of L3/HBM (~600-900cy). r9's iso-curve lesson:
//     register file caps bytes-in-flight, so the remaining lever is LATENCY
//     per load, which locality addresses.
//  2. v-loads issued AFTER the barrier (r9-proven): first exposed batch
//     shrinks 56->32 loads; v latency hides under combine+softmax; peak
//     VGPR drops ~124->~105 (same 128-plateau, no occupancy change).
__device__ __forceinline__ float dpp_up1(float x) {   // lane i <- i-1; lane0 <- 0
    return __int_as_float(
        __builtin_amdgcn_update_dpp(0, __float_as_int(x), 0x138, 0xF, 0xF, true));
}
__device__ __forceinline__ float dpp_dn1(float x) {   // lane i <- i+1; lane63 <- 0
    return __int_as_float(
        __builtin_amdgcn_update_dpp(0, __float_as_int(x), 0x130, 0xF, 0xF, true));
}

__global__ __launch_bounds__(256) void dilate_attn_kernel(
    const float* __restrict__ q,
    const float* __restrict__ k,
    const float* __restrict__ v,
    float* __restrict__ out)
{
    const int tx = threadIdx.x;            // 0..63 (pair within 2-row stripe)
    const int qc = threadIdx.y;            // 0..3 channel quarter (8 ch)
    const int flat = blockIdx.x;           // 0..2687
    const int work = (flat & 7) * 336 + (flat >> 3);   // bijective: 8*336=2688
    const int stripe = work % 28;
    const int bh     = work / 28;
    const int b = bh / NHEADS;
    const int head = bh - b * NHEADS;

    const int n0r = stripe * 112 + 2 * tx;
    const int n0 = (n0r <= NN - 2) ? n0r : NN - 2;   // clamp idle lanes
    const bool active = (tx < 56);

    const int y  = n0 / WW;
    const int x0 = n0 - y * WW;            // even; stripe base is row-aligned
    const float mlo = (x0 == 0)      ? 0.f : 1.f;
    const float mhi = (x0 == WW - 2) ? 0.f : 1.f;

    const int base0 = (b * CC + head * HD + qc * 8) * NN;

    __shared__ float2 part[4][64][9];      // 18432 B logit exchange

    // ---- prefetch q (8 ch) + k (3 rows x 8 ch): 32 float2 loads ----
    float2 qv[8];
#pragma unroll
    for (int d = 0; d < 8; ++d)
        qv[d] = *reinterpret_cast<const float2*>(q + base0 + d * NN + n0);

    float rm[3]; int rb[3];
#pragma unroll
    for (int r = 0; r < 3; ++r) {
        const int ny = y + (r - 1) * 2;
        rm[r] = ((unsigned)ny < HH) ? 1.f : 0.f;
        const int nyc = ny < 0 ? 0 : (ny > HH - 1 ? HH - 1 : ny);
        rb[r] = base0 + nyc * WW + x0;
    }

    float2 km[3][8];
#pragma unroll
    for (int r = 0; r < 3; ++r)
#pragma unroll
        for (int d = 0; d < 8; ++d)
            km[r][d] = *reinterpret_cast<const float2*>(k + rb[r] + d * NN);

    // ---- QK: center tap local, side taps via DPP wave shifts ----
    float lg[9][2];
#pragma unroll
    for (int r = 0; r < 3; ++r) {
        float s0x = 0.f, s0y = 0.f, s1x = 0.f, s1y = 0.f, s2x = 0.f, s2y = 0.f;
#pragma unroll
        for (int d = 0; d < 8; ++d) {
            const float2 w1 = km[r][d];
            const float w0x = dpp_up1(w1.x);
            const float w0y = dpp_up1(w1.y);
            const float w2x = dpp_dn1(w1.x);
            const float w2y = dpp_dn1(w1.y);
            s0x = fmaf(qv[d].x, w0x, s0x);  s0y = fmaf(qv[d].y, w0y, s0y);
            s1x = fmaf(qv[d].x, w1.x, s1x); s1y = fmaf(qv[d].y, w1.y, s1y);
            s2x = fmaf(qv[d].x, w2x, s2x);  s2y = fmaf(qv[d].y, w2y, s2y);
        }
        const float m0 = rm[r] * mlo, m2 = rm[r] * mhi;
        lg[r * 3 + 0][0] = s0x * m0;    lg[r * 3 + 0][1] = s0y * m0;
        lg[r * 3 + 1][0] = s1x * rm[r]; lg[r * 3 + 1][1] = s1y * rm[r];
        lg[r * 3 + 2][0] = s2x * m2;    lg[r * 3 + 2][1] = s2y * m2;
    }

    // ---- write partials, barrier ----
#pragma unroll
    for (int t = 0; t < 9; ++t) part[qc][tx][t] = make_float2(lg[t][0], lg[t][1]);
    __syncthreads();

    // ---- issue v loads NOW (into k's freed regs); latency hides under the
    //      combine + softmax below. sched_barrier pins the issue point. ----
    float2 vm[3][8];
#pragma unroll
    for (int r = 0; r < 3; ++r)
#pragma unroll
        for (int d = 0; d < 8; ++d)
            vm[r][d] = *reinterpret_cast<const float2*>(v + rb[r] + d * NN);
    __builtin_amdgcn_sched_barrier(0);

    // ---- combine quarters via LDS (27 float2 reads) ----
#pragma unroll
    for (int o = 1; o < 4; ++o) {
        const int oq = (qc + o) & 3;
#pragma unroll
        for (int t = 0; t < 9; ++t) {
            const float2 p = part[oq][tx][t];
            lg[t][0] += p.x; lg[t][1] += p.y;
        }
    }

    // ---- softmax over 9 taps (dup per quarter; cheap) ----
#pragma unroll
    for (int j = 0; j < 2; ++j) {
        float m = lg[0][j] * SCALE;
#pragma unroll
        for (int t = 0; t < 9; ++t) { lg[t][j] *= SCALE; m = fmaxf(m, lg[t][j]); }
        float s = 0.f;
#pragma unroll
        for (int t = 0; t < 9; ++t) { const float e = __expf(lg[t][j] - m); lg[t][j] = e; s += e; }
        const float inv = 1.f / s;
#pragma unroll
        for (int t = 0; t < 9; ++t) lg[t][j] *= inv;
    }
    // re-mask: invalid taps have nonzero softmax weight but v==0 in the ref
#pragma unroll
    for (int r = 0; r < 3; ++r) {
        const float m0 = rm[r] * mlo, m2 = rm[r] * mhi;
        lg[r * 3 + 0][0] *= m0;    lg[r * 3 + 0][1] *= m0;
        lg[r * 3 + 1][0] *= rm[r]; lg[r * 3 + 1][1] *= rm[r];
        lg[r * 3 + 2][0] *= m2;    lg[r * 3 + 2][1] *= m2;
    }

    // ---- PV: center tap local, side taps via DPP wave shifts ----
    float acc[8][2];
#pragma unroll
    for (int d = 0; d < 8; ++d) { acc[d][0] = 0.f; acc[d][1] = 0.f; }
#pragma unroll
    for (int r = 0; r < 3; ++r) {
        const float g0x = lg[r * 3 + 0][0], g0y = lg[r * 3 + 0][1];
        const float g1x = lg[r * 3 + 1][0], g1y = lg[r * 3 + 1][1];
        const float g2x = lg[r * 3 + 2][0], g2y = lg[r * 3 + 2][1];
#pragma unroll
        for (int d = 0; d < 8; ++d) {
            const float2 u1 = vm[r][d];
            const float u0x = dpp_up1(u1.x);
            const float u0y = dpp_up1(u1.y);
            const float u2x = dpp_dn1(u1.x);
            const float u2y = dpp_dn1(u1.y);
            acc[d][0] = fmaf(g0x, u0x, acc[d][0]);  acc[d][1] = fmaf(g0y, u0y, acc[d][1]);
            acc[d][0] = fmaf(g1x, u1.x, acc[d][0]); acc[d][1] = fmaf(g1y, u1.y, acc[d][1]);
            acc[d][0] = fmaf(g2x, u2x, acc[d][0]);  acc[d][1] = fmaf(g2y, u2y, acc[d][1]);
        }
    }

    // ---- store: out[b, y, x0+j, head*32 + qc*8 + 0..7] ----
    if (active) {
#pragma unroll
        for (int j = 0; j < 2; ++j) {
            float* ob = out + ((b * HH + y) * WW + (x0 + j)) * CC + head * HD + qc * 8;
            *reinterpret_cast<float4*>(ob)     = make_float4(acc[0][j], acc[1][j], acc[2][j], acc[3][j]);
            *reinterpret_cast<float4*>(ob + 4) = make_float4(acc[4][j], acc[5][j], acc[6][j], acc[7][j]);
        }
    }
}

extern "C" void kernel_launch(void* const* d_in, const int* in_sizes, int n_in,
                              void* d_out, int out_size, void* d_ws, size_t ws_size,
                              hipStream_t stream) {
    const float* q = (const float*)d_in[0];
    const float* k = (const float*)d_in[1];
    const float* v = (const float*)d_in[2];
    float* out = (float*)d_out;

    dim3 block(64, 4);                    // 256 threads
    dim3 grid(28 * BB * NHEADS);          // 2688 flat; XCD-swizzled in-kernel
    dilate_attn_kernel<<<grid, block, 0, stream>>>(q, k, v, out);
}